// Round 1
// baseline (569.082 us; speedup 1.0000x reference)
//
#include <hip/hip_runtime.h>
#include <hip/hip_bf16.h>
#include <stdint.h>

// ---------------------------------------------------------------------------
// Types / helpers
// ---------------------------------------------------------------------------
typedef __attribute__((ext_vector_type(8))) short bf16x8;
typedef __attribute__((ext_vector_type(4))) float f32x4;

#define GLB_AS __attribute__((address_space(1)))
#define LDS_AS __attribute__((address_space(3)))

__device__ __forceinline__ void g2l16(const void* g, void* l) {
  __builtin_amdgcn_global_load_lds((const GLB_AS void*)g, (LDS_AS void*)l, 16, 0, 0);
}

__device__ __forceinline__ unsigned short f2bf(float f) {
  union { __hip_bfloat16 h; unsigned short u; } cv;
  cv.h = __float2bfloat16(f);
  return cv.u;
}
__device__ __forceinline__ float bf2f(unsigned int u) {
  return __uint_as_float(u << 16);
}

// ---------------------------------------------------------------------------
// GEMM: C[M,N] = A[M,K] (bf16, row-major) * Bt[N,K]^T (bf16, row-major)
// 128x128 tile, BK=64, 4 waves (2x2 of 64x64), 16x16x32 MFMA, f32 accum.
// global_load_lds width-16 staging with XOR slot swizzle (conflict-free reads).
// OUT_BF16=1: write bf16 with scale; else f32.
// ---------------------------------------------------------------------------
#define BM 128
#define BN 128
#define BKG 64

template <int OUT_BF16>
__global__ __launch_bounds__(256)
void gemm_bt(const unsigned short* __restrict__ A,
             const unsigned short* __restrict__ Bt,
             void* __restrict__ C,
             int K, int lda, int ldb, int ldc,
             long long sA, long long sB, long long sC,
             float scale)
{
  __shared__ __attribute__((aligned(16))) short As[BM * BKG];
  __shared__ __attribute__((aligned(16))) short Bs[BN * BKG];

  const int tid = threadIdx.x;
  const int z = blockIdx.z;
  const unsigned short* Ab = A + (long long)z * sA + (long long)blockIdx.y * BM * lda;
  const unsigned short* Bb = Bt + (long long)z * sB + (long long)blockIdx.x * BN * ldb;

  const int lane = tid & 63, wid = tid >> 6;
  const int wr = wid >> 1, wc = wid & 1;
  const int l15 = lane & 15, l4 = lane >> 4;

  f32x4 acc[4][4];
#pragma unroll
  for (int i = 0; i < 4; ++i)
#pragma unroll
    for (int j = 0; j < 4; ++j) acc[i][j] = f32x4{0.f, 0.f, 0.f, 0.f};

  // staging addresses: chunk c = i*256+tid; row=c>>3, slot=c&7 (8 x 16B per 128B row)
  // LDS is linear (dest = wave-uniform + lane*16); source column is pre-swizzled
  // so that read-side XOR swizzle sees logical data (guide §5/m173/m201 pattern).
  const unsigned short* gAp[4];
  const unsigned short* gBp[4];
#pragma unroll
  for (int i = 0; i < 4; ++i) {
    int c = i * 256 + tid;
    int row = c >> 3, slot = c & 7;
    int gslot = slot ^ (row & 7);
    gAp[i] = Ab + (long long)row * lda + gslot * 8;
    gBp[i] = Bb + (long long)row * ldb + gslot * 8;
  }

  const int kTiles = K / BKG;
  for (int kt = 0; kt < kTiles; ++kt) {
    __syncthreads();  // previous tile's reads complete before overwrite
#pragma unroll
    for (int i = 0; i < 4; ++i)
      g2l16(gAp[i] + kt * BKG, (char*)As + i * 4096 + tid * 16);
#pragma unroll
    for (int i = 0; i < 4; ++i)
      g2l16(gBp[i] + kt * BKG, (char*)Bs + i * 4096 + tid * 16);
    __syncthreads();  // drains vmcnt; LDS ready

#pragma unroll
    for (int h = 0; h < 2; ++h) {
      bf16x8 af[4], bfr[4];
#pragma unroll
      for (int fr = 0; fr < 4; ++fr) {
        int row = wr * 64 + fr * 16 + l15;
        int slot = (h * 4 + l4) ^ (row & 7);
        af[fr] = *(const bf16x8*)((const char*)As + row * 128 + slot * 16);
      }
#pragma unroll
      for (int fc = 0; fc < 4; ++fc) {
        int row = wc * 64 + fc * 16 + l15;
        int slot = (h * 4 + l4) ^ (row & 7);
        bfr[fc] = *(const bf16x8*)((const char*)Bs + row * 128 + slot * 16);
      }
#pragma unroll
      for (int fr = 0; fr < 4; ++fr)
#pragma unroll
        for (int fc = 0; fc < 4; ++fc)
          acc[fr][fc] = __builtin_amdgcn_mfma_f32_16x16x32_bf16(
              af[fr], bfr[fc], acc[fr][fc], 0, 0, 0);
    }
  }

  // epilogue: C/D layout col=lane&15, row=(lane>>4)*4+reg  [m89]
  const long long m0 = (long long)blockIdx.y * BM + wr * 64;
  const long long n0 = (long long)blockIdx.x * BN + wc * 64;
  if (OUT_BF16) {
    unsigned short* Cc = (unsigned short*)C + (long long)z * sC;
#pragma unroll
    for (int fr = 0; fr < 4; ++fr)
#pragma unroll
      for (int fc = 0; fc < 4; ++fc)
#pragma unroll
        for (int i = 0; i < 4; ++i) {
          long long r = m0 + fr * 16 + l4 * 4 + i;
          long long col = n0 + fc * 16 + l15;
          Cc[r * ldc + col] = f2bf(acc[fr][fc][i] * scale);
        }
  } else {
    float* Cf = (float*)C + (long long)z * sC;
#pragma unroll
    for (int fr = 0; fr < 4; ++fr)
#pragma unroll
      for (int fc = 0; fc < 4; ++fc)
#pragma unroll
        for (int i = 0; i < 4; ++i) {
          long long r = m0 + fr * 16 + l4 * 4 + i;
          long long col = n0 + fc * 16 + l15;
          Cf[r * ldc + col] = acc[fr][fc][i];
        }
  }
}

// ---------------------------------------------------------------------------
// LayerNorm over rows of 1024 f32 -> bf16 (g,b applied). 1 block / row.
// ---------------------------------------------------------------------------
__global__ __launch_bounds__(256)
void ln_bf16(const float* __restrict__ in, unsigned short* __restrict__ out,
             const float* __restrict__ g, const float* __restrict__ b)
{
  const long long row = blockIdx.x;
  const int t = threadIdx.x;
  const float4 v = ((const float4*)(in + row * 1024))[t];
  float s = v.x + v.y + v.z + v.w;
  float ss = v.x * v.x + v.y * v.y + v.z * v.z + v.w * v.w;
#pragma unroll
  for (int o = 32; o >= 1; o >>= 1) {
    s += __shfl_xor(s, o);
    ss += __shfl_xor(ss, o);
  }
  __shared__ float red[8];
  if ((t & 63) == 0) { red[t >> 6] = s; red[4 + (t >> 6)] = ss; }
  __syncthreads();
  s = red[0] + red[1] + red[2] + red[3];
  ss = red[4] + red[5] + red[6] + red[7];
  const float mean = s * (1.f / 1024.f);
  const float var = ss * (1.f / 1024.f) - mean * mean;
  const float rs = rsqrtf(var + 1e-5f);
  const float4 gv = ((const float4*)g)[t];
  const float4 bv = ((const float4*)b)[t];
  ushort4 o4;
  o4.x = f2bf((v.x - mean) * rs * gv.x + bv.x);
  o4.y = f2bf((v.y - mean) * rs * gv.y + bv.y);
  o4.z = f2bf((v.z - mean) * rs * gv.z + bv.z);
  o4.w = f2bf((v.w - mean) * rs * gv.w + bv.w);
  ((ushort4*)(out + row * 1024))[t] = o4;
}

// ---------------------------------------------------------------------------
// Row softmax over 2048 bf16, in place. 1 block / row, 8 elems / thread.
// ---------------------------------------------------------------------------
__global__ __launch_bounds__(256)
void softmax_bf16(unsigned short* __restrict__ a)
{
  const long long row = blockIdx.x;
  unsigned short* p = a + row * 2048;
  const int t = threadIdx.x;
  uint4 pk = ((const uint4*)p)[t];
  float v[8];
  v[0] = bf2f(pk.x & 0xffffu); v[1] = bf2f(pk.x >> 16);
  v[2] = bf2f(pk.y & 0xffffu); v[3] = bf2f(pk.y >> 16);
  v[4] = bf2f(pk.z & 0xffffu); v[5] = bf2f(pk.z >> 16);
  v[6] = bf2f(pk.w & 0xffffu); v[7] = bf2f(pk.w >> 16);

  float m = v[0];
#pragma unroll
  for (int i = 1; i < 8; ++i) m = fmaxf(m, v[i]);
#pragma unroll
  for (int o = 32; o >= 1; o >>= 1) m = fmaxf(m, __shfl_xor(m, o));
  __shared__ float redm[4];
  if ((t & 63) == 0) redm[t >> 6] = m;
  __syncthreads();
  m = fmaxf(fmaxf(redm[0], redm[1]), fmaxf(redm[2], redm[3]));

  float e[8];
  float s = 0.f;
#pragma unroll
  for (int i = 0; i < 8; ++i) { e[i] = __expf(v[i] - m); s += e[i]; }
#pragma unroll
  for (int o = 32; o >= 1; o >>= 1) s += __shfl_xor(s, o);
  __shared__ float reds[4];
  if ((t & 63) == 0) reds[t >> 6] = s;
  __syncthreads();
  s = reds[0] + reds[1] + reds[2] + reds[3];
  const float inv = 1.f / s;

  pk.x = (unsigned int)f2bf(e[0] * inv) | ((unsigned int)f2bf(e[1] * inv) << 16);
  pk.y = (unsigned int)f2bf(e[2] * inv) | ((unsigned int)f2bf(e[3] * inv) << 16);
  pk.z = (unsigned int)f2bf(e[4] * inv) | ((unsigned int)f2bf(e[5] * inv) << 16);
  pk.w = (unsigned int)f2bf(e[6] * inv) | ((unsigned int)f2bf(e[7] * inv) << 16);
  ((uint4*)p)[t] = pk;
}

// ---------------------------------------------------------------------------
// Flat f32 -> bf16 cast (vectorized, grid-stride).
// ---------------------------------------------------------------------------
__global__ __launch_bounds__(256)
void cast_flat(const float* __restrict__ in, unsigned short* __restrict__ out, int n4)
{
  int idx = blockIdx.x * 256 + threadIdx.x;
  const int stride = gridDim.x * 256;
  for (; idx < n4; idx += stride) {
    float4 v = ((const float4*)in)[idx];
    ushort4 o;
    o.x = f2bf(v.x); o.y = f2bf(v.y); o.z = f2bf(v.z); o.w = f2bf(v.w);
    ((ushort4*)out)[idx] = o;
  }
}

// ---------------------------------------------------------------------------
// Transpose + cast: in f32 [Z][R][C] -> out bf16 [Z][C][R]. Block (32,8).
// ---------------------------------------------------------------------------
__global__ __launch_bounds__(256)
void transpose_cast(const float* __restrict__ in, unsigned short* __restrict__ out,
                    int R, int C)
{
  __shared__ float tile[32][33];
  const int z = blockIdx.z;
  const float* src = in + (long long)z * R * C;
  unsigned short* dst = out + (long long)z * R * C;
  const int tx = threadIdx.x, ty = threadIdx.y;
  const int c0 = blockIdx.x * 32, r0 = blockIdx.y * 32;
#pragma unroll
  for (int k = 0; k < 4; ++k)
    tile[ty + 8 * k][tx] = src[(long long)(r0 + ty + 8 * k) * C + c0 + tx];
  __syncthreads();
#pragma unroll
  for (int k = 0; k < 4; ++k)
    dst[(long long)(c0 + ty + 8 * k) * R + r0 + tx] = f2bf(tile[tx][ty + 8 * k]);
}

// ---------------------------------------------------------------------------
// Launch
// ---------------------------------------------------------------------------
extern "C" void kernel_launch(void* const* d_in, const int* in_sizes, int n_in,
                              void* d_out, int out_size, void* d_ws, size_t ws_size,
                              hipStream_t stream)
{
  const float* X = (const float*)d_in[0];
  const float* Y = (const float*)d_in[1];
  const float* Kw = (const float*)d_in[2];
  const float* Qw = (const float*)d_in[3];
  const float* g1 = (const float*)d_in[4];
  const float* b1 = (const float*)d_in[5];
  const float* g2 = (const float*)d_in[6];
  const float* b2 = (const float*)d_in[7];
  float* out = (float*)d_out;

  // workspace layout (196 MB):
  //  [0,64M)       temp f32 proj output  /  later: alpha bf16 [8,2048,2048]
  //  [64M,96M)     keys bf16 [16384,1024]
  //  [96M,128M)    X bf16 [16384,1024]
  //  [128M,160M)   Y bf16 (proj1 A), later overwritten by queries bf16
  //  [160M,192M)   Yt bf16 [8,1024,2048]
  //  [192M,194M)   Kt bf16 [1024,1024]
  //  [194M,196M)   Qt bf16 [1024,1024]
  char* ws = (char*)d_ws;
  float* tempf = (float*)ws;
  unsigned short* alpha = (unsigned short*)ws;
  unsigned short* keys = (unsigned short*)(ws + (64ll << 20));
  unsigned short* xb   = (unsigned short*)(ws + (96ll << 20));
  unsigned short* ybq  = (unsigned short*)(ws + (128ll << 20));
  unsigned short* yt   = (unsigned short*)(ws + (160ll << 20));
  unsigned short* ktw  = (unsigned short*)(ws + (192ll << 20));
  unsigned short* qtw  = (unsigned short*)(ws + (194ll << 20));

  const int n4 = 16777216 / 4;  // 8*2048*1024 / 4

  // 1. casts
  cast_flat<<<2048, 256, 0, stream>>>(Y, ybq, n4);
  cast_flat<<<2048, 256, 0, stream>>>(X, xb, n4);
  transpose_cast<<<dim3(32, 32, 1), dim3(32, 8), 0, stream>>>(Kw, ktw, 1024, 1024);
  transpose_cast<<<dim3(32, 32, 1), dim3(32, 8), 0, stream>>>(Qw, qtw, 1024, 1024);
  transpose_cast<<<dim3(32, 64, 8), dim3(32, 8), 0, stream>>>(Y, yt, 2048, 1024);

  // 2. keys = LN(Y @ K)
  gemm_bt<0><<<dim3(8, 128, 1), 256, 0, stream>>>(
      ybq, ktw, tempf, 1024, 1024, 1024, 1024, 0, 0, 0, 1.f);
  ln_bf16<<<16384, 256, 0, stream>>>(tempf, keys, g1, b1);

  // 3. queries = LN(X @ Q)   (queries overwrite the Ybf16 region)
  gemm_bt<0><<<dim3(8, 128, 1), 256, 0, stream>>>(
      xb, qtw, tempf, 1024, 1024, 1024, 1024, 0, 0, 0, 1.f);
  ln_bf16<<<16384, 256, 0, stream>>>(tempf, ybq, g2, b2);

  // 4. alpha = queries @ keys^T / 1024  (bf16, into temp region)
  gemm_bt<1><<<dim3(16, 16, 8), 256, 0, stream>>>(
      ybq, keys, alpha, 1024, 1024, 1024, 2048,
      2048ll * 1024, 2048ll * 1024, 2048ll * 2048, 1.f / 1024.f);

  // 5. softmax rows
  softmax_bf16<<<16384, 256, 0, stream>>>(alpha);

  // 6. out = alpha @ Y   (B^T = Yt)
  gemm_bt<0><<<dim3(8, 16, 8), 256, 0, stream>>>(
      alpha, yt, out, 2048, 2048, 2048, 1024,
      2048ll * 2048, 1024ll * 2048, 2048ll * 1024, 1.f);
}

// Round 3
// 546.660 us; speedup vs baseline: 1.0410x; 1.0410x over previous
//
#include <hip/hip_runtime.h>
#include <hip/hip_bf16.h>
#include <stdint.h>

// ---------------------------------------------------------------------------
// Types / helpers
// ---------------------------------------------------------------------------
typedef __attribute__((ext_vector_type(8))) short bf16x8;
typedef __attribute__((ext_vector_type(4))) float f32x4;

#define GLB_AS __attribute__((address_space(1)))
#define LDS_AS __attribute__((address_space(3)))

__device__ __forceinline__ void g2l16(const void* g, void* l) {
  __builtin_amdgcn_global_load_lds((const GLB_AS void*)g, (LDS_AS void*)l, 16, 0, 0);
}

__device__ __forceinline__ unsigned short f2bf(float f) {
  union { __hip_bfloat16 h; unsigned short u; } cv;
  cv.h = __float2bfloat16(f);
  return cv.u;
}
__device__ __forceinline__ float bf2f(unsigned int u) {
  return __uint_as_float(u << 16);
}

// ---------------------------------------------------------------------------
// GEMM: C[M,N] = A[M,K] (bf16, row-major) * Bt[N,K]^T (bf16, row-major)
// 128x128 tile, BK=64, 4 waves (2x2 of 64x64), 16x16x32 MFMA, f32 accum.
// global_load_lds width-16 staging with XOR slot swizzle (conflict-free reads).
// 1-D launch + bijective XCD-chunked swizzle (T1): consecutive logical tiles
// (which share A panels / B panels) are pinned to one XCD's L2.
// OUT_BF16=1: write bf16 with scale; else f32.
// ---------------------------------------------------------------------------
#define BM 128
#define BN 128
#define BKG 64

template <int OUT_BF16>
__global__ __launch_bounds__(256)
void gemm_bt(const unsigned short* __restrict__ A,
             const unsigned short* __restrict__ Bt,
             void* __restrict__ C,
             int K, int lda, int ldb, int ldc,
             long long sA, long long sB, long long sC,
             float scale, int gx, int gy)
{
  __shared__ __attribute__((aligned(16))) short As[BM * BKG];
  __shared__ __attribute__((aligned(16))) short Bs[BN * BKG];

  // XCD-chunked bijective swizzle (nwg is always a multiple of 8 here).
  const int nwg = gridDim.x;
  const int bid = blockIdx.x;
  const int wgid = (bid & 7) * (nwg >> 3) + (bid >> 3);
  const int tx = wgid % gx;
  const int rest = wgid / gx;
  const int ty = rest % gy;
  const int tz = rest / gy;

  const int tid = threadIdx.x;
  const unsigned short* Ab = A + (long long)tz * sA + (long long)ty * BM * lda;
  const unsigned short* Bb = Bt + (long long)tz * sB + (long long)tx * BN * ldb;

  const int lane = tid & 63, wid = tid >> 6;
  const int wr = wid >> 1, wc = wid & 1;
  const int l15 = lane & 15, l4 = lane >> 4;

  f32x4 acc[4][4];
#pragma unroll
  for (int i = 0; i < 4; ++i)
#pragma unroll
    for (int j = 0; j < 4; ++j) acc[i][j] = f32x4{0.f, 0.f, 0.f, 0.f};

  // staging addresses: chunk c = i*256+tid; row=c>>3, slot=c&7 (8 x 16B per 128B row)
  // LDS dest is linear (wave-uniform + lane*16); the global source column is
  // pre-swizzled so the read-side XOR sees logical data (m173/m201 pattern).
  const unsigned short* gAp[4];
  const unsigned short* gBp[4];
#pragma unroll
  for (int i = 0; i < 4; ++i) {
    int c = i * 256 + tid;
    int row = c >> 3, slot = c & 7;
    int gslot = slot ^ (row & 7);
    gAp[i] = Ab + (long long)row * lda + gslot * 8;
    gBp[i] = Bb + (long long)row * ldb + gslot * 8;
  }

  const int kTiles = K / BKG;
  for (int kt = 0; kt < kTiles; ++kt) {
    __syncthreads();  // previous tile's reads complete before overwrite
#pragma unroll
    for (int i = 0; i < 4; ++i)
      g2l16(gAp[i] + kt * BKG, (char*)As + i * 4096 + tid * 16);
#pragma unroll
    for (int i = 0; i < 4; ++i)
      g2l16(gBp[i] + kt * BKG, (char*)Bs + i * 4096 + tid * 16);
    __syncthreads();  // drains vmcnt; LDS ready

#pragma unroll
    for (int h = 0; h < 2; ++h) {
      bf16x8 af[4], bfr[4];
#pragma unroll
      for (int fr = 0; fr < 4; ++fr) {
        int row = wr * 64 + fr * 16 + l15;
        int slot = (h * 4 + l4) ^ (row & 7);
        af[fr] = *(const bf16x8*)((const char*)As + row * 128 + slot * 16);
      }
#pragma unroll
      for (int fc = 0; fc < 4; ++fc) {
        int row = wc * 64 + fc * 16 + l15;
        int slot = (h * 4 + l4) ^ (row & 7);
        bfr[fc] = *(const bf16x8*)((const char*)Bs + row * 128 + slot * 16);
      }
#pragma unroll
      for (int fr = 0; fr < 4; ++fr)
#pragma unroll
        for (int fc = 0; fc < 4; ++fc)
          acc[fr][fc] = __builtin_amdgcn_mfma_f32_16x16x32_bf16(
              af[fr], bfr[fc], acc[fr][fc], 0, 0, 0);
    }
  }

  // epilogue: C/D layout col=lane&15, row=(lane>>4)*4+reg  [m89]
  const long long m0 = (long long)ty * BM + wr * 64;
  const long long n0 = (long long)tx * BN + wc * 64;
  if (OUT_BF16) {
    unsigned short* Cc = (unsigned short*)C + (long long)tz * sC;
#pragma unroll
    for (int fr = 0; fr < 4; ++fr)
#pragma unroll
      for (int fc = 0; fc < 4; ++fc)
#pragma unroll
        for (int i = 0; i < 4; ++i) {
          long long r = m0 + fr * 16 + l4 * 4 + i;
          long long col = n0 + fc * 16 + l15;
          Cc[r * ldc + col] = f2bf(acc[fr][fc][i] * scale);
        }
  } else {
    float* Cf = (float*)C + (long long)tz * sC;
#pragma unroll
    for (int fr = 0; fr < 4; ++fr)
#pragma unroll
      for (int fc = 0; fc < 4; ++fc)
#pragma unroll
        for (int i = 0; i < 4; ++i) {
          long long r = m0 + fr * 16 + l4 * 4 + i;
          long long col = n0 + fc * 16 + l15;
          Cf[r * ldc + col] = acc[fr][fc][i];
        }
  }
}

// ---------------------------------------------------------------------------
// LayerNorm over rows of 1024 f32 -> bf16 (g,b applied). 1 block / row.
// ---------------------------------------------------------------------------
__global__ __launch_bounds__(256)
void ln_bf16(const float* __restrict__ in, unsigned short* __restrict__ out,
             const float* __restrict__ g, const float* __restrict__ b)
{
  const long long row = blockIdx.x;
  const int t = threadIdx.x;
  const float4 v = ((const float4*)(in + row * 1024))[t];
  float s = v.x + v.y + v.z + v.w;
  float ss = v.x * v.x + v.y * v.y + v.z * v.z + v.w * v.w;
#pragma unroll
  for (int o = 32; o >= 1; o >>= 1) {
    s += __shfl_xor(s, o);
    ss += __shfl_xor(ss, o);
  }
  __shared__ float red[8];
  if ((t & 63) == 0) { red[t >> 6] = s; red[4 + (t >> 6)] = ss; }
  __syncthreads();
  s = red[0] + red[1] + red[2] + red[3];
  ss = red[4] + red[5] + red[6] + red[7];
  const float mean = s * (1.f / 1024.f);
  const float var = ss * (1.f / 1024.f) - mean * mean;
  const float rs = rsqrtf(var + 1e-5f);
  const float4 gv = ((const float4*)g)[t];
  const float4 bv = ((const float4*)b)[t];
  ushort4 o4;
  o4.x = f2bf((v.x - mean) * rs * gv.x + bv.x);
  o4.y = f2bf((v.y - mean) * rs * gv.y + bv.y);
  o4.z = f2bf((v.z - mean) * rs * gv.z + bv.z);
  o4.w = f2bf((v.w - mean) * rs * gv.w + bv.w);
  ((ushort4*)(out + row * 1024))[t] = o4;
}

// ---------------------------------------------------------------------------
// Row softmax over 2048 bf16, in place. 1 block / row, 8 elems / thread.
// ---------------------------------------------------------------------------
__global__ __launch_bounds__(256)
void softmax_bf16(unsigned short* __restrict__ a)
{
  const long long row = blockIdx.x;
  unsigned short* p = a + row * 2048;
  const int t = threadIdx.x;
  uint4 pk = ((const uint4*)p)[t];
  float v[8];
  v[0] = bf2f(pk.x & 0xffffu); v[1] = bf2f(pk.x >> 16);
  v[2] = bf2f(pk.y & 0xffffu); v[3] = bf2f(pk.y >> 16);
  v[4] = bf2f(pk.z & 0xffffu); v[5] = bf2f(pk.z >> 16);
  v[6] = bf2f(pk.w & 0xffffu); v[7] = bf2f(pk.w >> 16);

  float m = v[0];
#pragma unroll
  for (int i = 1; i < 8; ++i) m = fmaxf(m, v[i]);
#pragma unroll
  for (int o = 32; o >= 1; o >>= 1) m = fmaxf(m, __shfl_xor(m, o));
  __shared__ float redm[4];
  if ((t & 63) == 0) redm[t >> 6] = m;
  __syncthreads();
  m = fmaxf(fmaxf(redm[0], redm[1]), fmaxf(redm[2], redm[3]));

  float e[8];
  float s = 0.f;
#pragma unroll
  for (int i = 0; i < 8; ++i) { e[i] = __expf(v[i] - m); s += e[i]; }
#pragma unroll
  for (int o = 32; o >= 1; o >>= 1) s += __shfl_xor(s, o);
  __shared__ float reds[4];
  if ((t & 63) == 0) reds[t >> 6] = s;
  __syncthreads();
  s = reds[0] + reds[1] + reds[2] + reds[3];
  const float inv = 1.f / s;

  pk.x = (unsigned int)f2bf(e[0] * inv) | ((unsigned int)f2bf(e[1] * inv) << 16);
  pk.y = (unsigned int)f2bf(e[2] * inv) | ((unsigned int)f2bf(e[3] * inv) << 16);
  pk.z = (unsigned int)f2bf(e[4] * inv) | ((unsigned int)f2bf(e[5] * inv) << 16);
  pk.w = (unsigned int)f2bf(e[6] * inv) | ((unsigned int)f2bf(e[7] * inv) << 16);
  ((uint4*)p)[t] = pk;
}

// ---------------------------------------------------------------------------
// Flat f32 -> bf16 cast (vectorized, grid-stride).
// ---------------------------------------------------------------------------
__global__ __launch_bounds__(256)
void cast_flat(const float* __restrict__ in, unsigned short* __restrict__ out, int n4)
{
  int idx = blockIdx.x * 256 + threadIdx.x;
  const int stride = gridDim.x * 256;
  for (; idx < n4; idx += stride) {
    float4 v = ((const float4*)in)[idx];
    ushort4 o;
    o.x = f2bf(v.x); o.y = f2bf(v.y); o.z = f2bf(v.z); o.w = f2bf(v.w);
    ((ushort4*)out)[idx] = o;
  }
}

// ---------------------------------------------------------------------------
// Transpose + cast: in f32 [Z][R][C] -> out bf16 [Z][C][R]. Block (32,8).
// ---------------------------------------------------------------------------
__global__ __launch_bounds__(256)
void transpose_cast(const float* __restrict__ in, unsigned short* __restrict__ out,
                    int R, int C)
{
  __shared__ float tile[32][33];
  const int z = blockIdx.z;
  const float* src = in + (long long)z * R * C;
  unsigned short* dst = out + (long long)z * R * C;
  const int tx = threadIdx.x, ty = threadIdx.y;
  const int c0 = blockIdx.x * 32, r0 = blockIdx.y * 32;
#pragma unroll
  for (int k = 0; k < 4; ++k)
    tile[ty + 8 * k][tx] = src[(long long)(r0 + ty + 8 * k) * C + c0 + tx];
  __syncthreads();
#pragma unroll
  for (int k = 0; k < 4; ++k)
    dst[(long long)(c0 + ty + 8 * k) * R + r0 + tx] = f2bf(tile[tx][ty + 8 * k]);
}

// ---------------------------------------------------------------------------
// Launch
// ---------------------------------------------------------------------------
extern "C" void kernel_launch(void* const* d_in, const int* in_sizes, int n_in,
                              void* d_out, int out_size, void* d_ws, size_t ws_size,
                              hipStream_t stream)
{
  const float* X = (const float*)d_in[0];
  const float* Y = (const float*)d_in[1];
  const float* Kw = (const float*)d_in[2];
  const float* Qw = (const float*)d_in[3];
  const float* g1 = (const float*)d_in[4];
  const float* b1 = (const float*)d_in[5];
  const float* g2 = (const float*)d_in[6];
  const float* b2 = (const float*)d_in[7];
  float* out = (float*)d_out;

  // workspace layout (196 MB):
  //  [0,64M)       temp f32 proj output  /  later: alpha bf16 [8,2048,2048]
  //  [64M,96M)     keys bf16 [16384,1024]
  //  [96M,128M)    X bf16 [16384,1024]
  //  [128M,160M)   Y bf16 (proj1 A), later overwritten by queries bf16
  //  [160M,192M)   Yt bf16 [8,1024,2048]
  //  [192M,194M)   Kt bf16 [1024,1024]
  //  [194M,196M)   Qt bf16 [1024,1024]
  char* ws = (char*)d_ws;
  float* tempf = (float*)ws;
  unsigned short* alpha = (unsigned short*)ws;
  unsigned short* keys = (unsigned short*)(ws + (64ll << 20));
  unsigned short* xb   = (unsigned short*)(ws + (96ll << 20));
  unsigned short* ybq  = (unsigned short*)(ws + (128ll << 20));
  unsigned short* yt   = (unsigned short*)(ws + (160ll << 20));
  unsigned short* ktw  = (unsigned short*)(ws + (192ll << 20));
  unsigned short* qtw  = (unsigned short*)(ws + (194ll << 20));

  const int n4 = 16777216 / 4;  // 8*2048*1024 / 4

  // 1. casts
  cast_flat<<<2048, 256, 0, stream>>>(Y, ybq, n4);
  cast_flat<<<2048, 256, 0, stream>>>(X, xb, n4);
  transpose_cast<<<dim3(32, 32, 1), dim3(32, 8), 0, stream>>>(Kw, ktw, 1024, 1024);
  transpose_cast<<<dim3(32, 32, 1), dim3(32, 8), 0, stream>>>(Qw, qtw, 1024, 1024);
  transpose_cast<<<dim3(32, 64, 8), dim3(32, 8), 0, stream>>>(Y, yt, 2048, 1024);

  // 2. keys = LN(Y @ K)   — grid 8x128 = 1024 blocks, 1-D + XCD swizzle
  gemm_bt<0><<<1024, 256, 0, stream>>>(
      ybq, ktw, tempf, 1024, 1024, 1024, 1024, 0, 0, 0, 1.f, 8, 128);
  ln_bf16<<<16384, 256, 0, stream>>>(tempf, keys, g1, b1);

  // 3. queries = LN(X @ Q)   (queries overwrite the Ybf16 region)
  gemm_bt<0><<<1024, 256, 0, stream>>>(
      xb, qtw, tempf, 1024, 1024, 1024, 1024, 0, 0, 0, 1.f, 8, 128);
  ln_bf16<<<16384, 256, 0, stream>>>(tempf, ybq, g2, b2);

  // 4. alpha = queries @ keys^T / 1024  (bf16, into temp region)
  //    grid 16x16x8 = 2048 blocks: one batch per XCD chunk
  gemm_bt<1><<<2048, 256, 0, stream>>>(
      ybq, keys, alpha, 1024, 1024, 1024, 2048,
      2048ll * 1024, 2048ll * 1024, 2048ll * 2048, 1.f / 1024.f, 16, 16);

  // 5. softmax rows
  softmax_bf16<<<16384, 256, 0, stream>>>(alpha);

  // 6. out = alpha @ Y   (B^T = Yt)  — grid 8x16x8 = 1024 blocks
  gemm_bt<0><<<1024, 256, 0, stream>>>(
      alpha, yt, out, 2048, 2048, 2048, 1024,
      2048ll * 2048, 1024ll * 2048, 2048ll * 1024, 1.f, 8, 16);
}

// Round 5
// 494.167 us; speedup vs baseline: 1.1516x; 1.1062x over previous
//
#include <hip/hip_runtime.h>
#include <hip/hip_bf16.h>
#include <stdint.h>

// ---------------------------------------------------------------------------
// Types / helpers
// ---------------------------------------------------------------------------
typedef __attribute__((ext_vector_type(8))) short bf16x8;
typedef __attribute__((ext_vector_type(4))) float f32x4;

#define GLB_AS __attribute__((address_space(1)))
#define LDS_AS __attribute__((address_space(3)))

__device__ __forceinline__ void g2l16(const void* g, void* l) {
  __builtin_amdgcn_global_load_lds((const GLB_AS void*)g, (LDS_AS void*)l, 16, 0, 0);
}

__device__ __forceinline__ unsigned short f2bf(float f) {
  union { __hip_bfloat16 h; unsigned short u; } cv;
  cv.h = __float2bfloat16(f);
  return cv.u;
}
__device__ __forceinline__ float bf2f(unsigned int u) {
  return __uint_as_float(u << 16);
}

// ---------------------------------------------------------------------------
// 256x256-tile GEMM, 8 waves (2M x 4N), K-step 32, 4-deep LDS pipeline.
//   C[M,N] = A[M,K](bf16 rm) * Bt[N,K]^T(bf16 rm), f32 accum.
// Schedule (T2+T3+T4+T5): per K-step 2 phases of 16 MFMA; prefetch issued
// 3 steps ahead via global_load_lds w16; counted s_waitcnt vmcnt(8) once per
// step placed BEFORE the step-end s_barrier (all waves confirm their own
// loads before anyone reads the slot); raw s_barrier (no vmcnt(0) drain).
// LDS slot layout: [256 rows][32 cols bf16] per operand, row = 4x16B groups,
// physical group p = (logical_kgroup + row) & 3  -> 2 lanes/bank (free).
// Staging: linear LDS dest (tid*16), global source pre-inverse-swizzled.
// ---------------------------------------------------------------------------
template <int OUT_BF16>
__global__ __launch_bounds__(512, 2)
void gemm256(const unsigned short* __restrict__ A,
             const unsigned short* __restrict__ Bt,
             void* __restrict__ C,
             int K, int lda, int ldb, int ldc,
             long long sA, long long sB, long long sC,
             float scale, int gx, int gy)
{
  __shared__ __attribute__((aligned(16))) char lds[131072];  // 4 slots x (A 16K + B 16K)

  // XCD-chunked bijective swizzle (grid always a multiple of 8 here).
  const int nwg = gridDim.x;
  const int bid = blockIdx.x;
  const int wgid = (bid & 7) * (nwg >> 3) + (bid >> 3);
  const int bx = wgid % gx;
  const int rest = wgid / gx;
  const int by = rest % gy;
  const int bz = rest / gy;

  const int tid = threadIdx.x;
  const int lane = tid & 63, wid = tid >> 6;
  const int wr = wid >> 2, wc = wid & 3;           // wave tile: 128 rows x 64 cols
  const int l15 = lane & 15, l4 = lane >> 4;

  const unsigned short* Ab = A + (long long)bz * sA + (long long)by * 256 * lda;
  const unsigned short* Bb = Bt + (long long)bz * sB + (long long)bx * 256 * ldb;

  // staging constants: 2 chunks/thread per 16KB half (1024 chunks of 16B).
  // chunk c: row = c>>2, phys group p = c&3, logical k-group q = (p - row)&3.
  const int c0 = tid, c1 = 512 + tid;
  const int r0 = c0 >> 2, q0 = ((c0 & 3) - r0) & 3;
  const int r1 = c1 >> 2, q1 = ((c1 & 3) - r1) & 3;
  const unsigned short* gA0 = Ab + (long long)r0 * lda + q0 * 8;
  const unsigned short* gA1 = Ab + (long long)r1 * lda + q1 * 8;
  const unsigned short* gB0 = Bb + (long long)r0 * ldb + q0 * 8;
  const unsigned short* gB1 = Bb + (long long)r1 * ldb + q1 * 8;
  const int dc0 = c0 * 16, dc1 = c1 * 16;

#define STAGE_A(slot_, kt_)                                        \
  do {                                                             \
    char* base_ = lds + (slot_) * 32768;                           \
    g2l16(gA0 + (kt_) * 32, base_ + dc0);                          \
    g2l16(gA1 + (kt_) * 32, base_ + dc1);                          \
  } while (0)
#define STAGE_B(slot_, kt_)                                        \
  do {                                                             \
    char* base_ = lds + (slot_) * 32768 + 16384;                   \
    g2l16(gB0 + (kt_) * 32, base_ + dc0);                          \
    g2l16(gB1 + (kt_) * 32, base_ + dc1);                          \
  } while (0)

  f32x4 acc[8][4];
#pragma unroll
  for (int m = 0; m < 8; ++m)
#pragma unroll
    for (int n = 0; n < 4; ++n) acc[m][n] = f32x4{0.f, 0.f, 0.f, 0.f};

  const int nst = K / 32;

  // prologue: stage steps 0,1,2 (issue order = steady-state order)
  STAGE_A(0, 0); STAGE_B(0, 0);
  STAGE_A(1, 1); STAGE_B(1, 1);
  STAGE_A(2, 2); STAGE_B(2, 2);
  asm volatile("s_waitcnt vmcnt(8)" ::: "memory");   // step-0 A,B landed
  __builtin_amdgcn_sched_barrier(0);
  __builtin_amdgcn_s_barrier();
  __builtin_amdgcn_sched_barrier(0);

  bf16x8 a[8], b[4];
  for (int t = 0; t < nst; ++t) {
    const int s = t & 3;
    const char* sbA = lds + s * 32768;
    const char* sbB = sbA + 16384;

    // ---- phase A: read a[0..3], b[0..3]; prefetch A(t+3); 16 MFMA (m0-3)
#pragma unroll
    for (int m = 0; m < 4; ++m) {
      int r = wr * 128 + m * 16 + l15;
      a[m] = *(const bf16x8*)(sbA + r * 64 + (((l4 + r) & 3) << 4));
    }
#pragma unroll
    for (int n = 0; n < 4; ++n) {
      int r = wc * 64 + n * 16 + l15;
      b[n] = *(const bf16x8*)(sbB + r * 64 + (((l4 + r) & 3) << 4));
    }
    if (t + 3 < nst) STAGE_A((t + 3) & 3, t + 3);
    __builtin_amdgcn_sched_barrier(0);
    __builtin_amdgcn_s_barrier();
    __builtin_amdgcn_sched_barrier(0);
    __builtin_amdgcn_s_setprio(1);
#pragma unroll
    for (int m = 0; m < 4; ++m)
#pragma unroll
      for (int n = 0; n < 4; ++n)
        acc[m][n] = __builtin_amdgcn_mfma_f32_16x16x32_bf16(a[m], b[n], acc[m][n], 0, 0, 0);
    __builtin_amdgcn_s_setprio(0);
    __builtin_amdgcn_sched_barrier(0);
    __builtin_amdgcn_s_barrier();
    __builtin_amdgcn_sched_barrier(0);

    // ---- phase B: read a[4..7]; prefetch B(t+3); 16 MFMA (m4-7)
#pragma unroll
    for (int m = 4; m < 8; ++m) {
      int r = wr * 128 + m * 16 + l15;
      a[m] = *(const bf16x8*)(sbA + r * 64 + (((l4 + r) & 3) << 4));
    }
    if (t + 3 < nst) STAGE_B((t + 3) & 3, t + 3);
    __builtin_amdgcn_sched_barrier(0);
    __builtin_amdgcn_s_barrier();
    __builtin_amdgcn_sched_barrier(0);
    __builtin_amdgcn_s_setprio(1);
#pragma unroll
    for (int m = 4; m < 8; ++m)
#pragma unroll
      for (int n = 0; n < 4; ++n)
        acc[m][n] = __builtin_amdgcn_mfma_f32_16x16x32_bf16(a[m], b[n], acc[m][n], 0, 0, 0);
    __builtin_amdgcn_s_setprio(0);
    // counted wait for NEXT step's slot, before the step-end barrier:
    // outstanding = 4*f loads (f = staged future steps); drain oldest 4.
    if (t + 1 < nst) {
      int f = nst - 1 - t; if (f > 3) f = 3;
      if (f == 3)      asm volatile("s_waitcnt vmcnt(8)" ::: "memory");
      else if (f == 2) asm volatile("s_waitcnt vmcnt(4)" ::: "memory");
      else             asm volatile("s_waitcnt vmcnt(0)" ::: "memory");
    }
    __builtin_amdgcn_sched_barrier(0);
    __builtin_amdgcn_s_barrier();
    __builtin_amdgcn_sched_barrier(0);
  }
#undef STAGE_A
#undef STAGE_B

  // epilogue: C/D layout col = n0+n*16+l15, row = m0+m*16+l4*4+i  [m89]
  const long long m0 = (long long)by * 256 + wr * 128;
  const long long n0 = (long long)bx * 256 + wc * 64;
  if (OUT_BF16) {
    unsigned short* Cc = (unsigned short*)C + (long long)bz * sC;
#pragma unroll
    for (int m = 0; m < 8; ++m)
#pragma unroll
      for (int n = 0; n < 4; ++n)
#pragma unroll
        for (int i = 0; i < 4; ++i) {
          long long r = m0 + m * 16 + l4 * 4 + i;
          long long col = n0 + n * 16 + l15;
          Cc[r * ldc + col] = f2bf(acc[m][n][i] * scale);
        }
  } else {
    float* Cf = (float*)C + (long long)bz * sC;
#pragma unroll
    for (int m = 0; m < 8; ++m)
#pragma unroll
      for (int n = 0; n < 4; ++n)
#pragma unroll
        for (int i = 0; i < 4; ++i) {
          long long r = m0 + m * 16 + l4 * 4 + i;
          long long col = n0 + n * 16 + l15;
          Cf[r * ldc + col] = acc[m][n][i];
        }
  }
}

// ---------------------------------------------------------------------------
// LayerNorm over rows of 1024 f32 -> bf16 (g,b applied). 1 block / row.
// ---------------------------------------------------------------------------
__global__ __launch_bounds__(256)
void ln_bf16(const float* __restrict__ in, unsigned short* __restrict__ out,
             const float* __restrict__ g, const float* __restrict__ b)
{
  const long long row = blockIdx.x;
  const int t = threadIdx.x;
  const float4 v = ((const float4*)(in + row * 1024))[t];
  float s = v.x + v.y + v.z + v.w;
  float ss = v.x * v.x + v.y * v.y + v.z * v.z + v.w * v.w;
#pragma unroll
  for (int o = 32; o >= 1; o >>= 1) {
    s += __shfl_xor(s, o);
    ss += __shfl_xor(ss, o);
  }
  __shared__ float red[8];
  if ((t & 63) == 0) { red[t >> 6] = s; red[4 + (t >> 6)] = ss; }
  __syncthreads();
  s = red[0] + red[1] + red[2] + red[3];
  ss = red[4] + red[5] + red[6] + red[7];
  const float mean = s * (1.f / 1024.f);
  const float var = ss * (1.f / 1024.f) - mean * mean;
  const float rs = rsqrtf(var + 1e-5f);
  const float4 gv = ((const float4*)g)[t];
  const float4 bv = ((const float4*)b)[t];
  ushort4 o4;
  o4.x = f2bf((v.x - mean) * rs * gv.x + bv.x);
  o4.y = f2bf((v.y - mean) * rs * gv.y + bv.y);
  o4.z = f2bf((v.z - mean) * rs * gv.z + bv.z);
  o4.w = f2bf((v.w - mean) * rs * gv.w + bv.w);
  ((ushort4*)(out + row * 1024))[t] = o4;
}

// ---------------------------------------------------------------------------
// Row softmax over 2048 bf16, in place. 1 block / row, 8 elems / thread.
// ---------------------------------------------------------------------------
__global__ __launch_bounds__(256)
void softmax_bf16(unsigned short* __restrict__ a)
{
  const long long row = blockIdx.x;
  unsigned short* p = a + row * 2048;
  const int t = threadIdx.x;
  uint4 pk = ((const uint4*)p)[t];
  float v[8];
  v[0] = bf2f(pk.x & 0xffffu); v[1] = bf2f(pk.x >> 16);
  v[2] = bf2f(pk.y & 0xffffu); v[3] = bf2f(pk.y >> 16);
  v[4] = bf2f(pk.z & 0xffffu); v[5] = bf2f(pk.z >> 16);
  v[6] = bf2f(pk.w & 0xffffu); v[7] = bf2f(pk.w >> 16);

  float m = v[0];
#pragma unroll
  for (int i = 1; i < 8; ++i) m = fmaxf(m, v[i]);
#pragma unroll
  for (int o = 32; o >= 1; o >>= 1) m = fmaxf(m, __shfl_xor(m, o));
  __shared__ float redm[4];
  if ((t & 63) == 0) redm[t >> 6] = m;
  __syncthreads();
  m = fmaxf(fmaxf(redm[0], redm[1]), fmaxf(redm[2], redm[3]));

  float e[8];
  float s = 0.f;
#pragma unroll
  for (int i = 0; i < 8; ++i) { e[i] = __expf(v[i] - m); s += e[i]; }
#pragma unroll
  for (int o = 32; o >= 1; o >>= 1) s += __shfl_xor(s, o);
  __shared__ float reds[4];
  if ((t & 63) == 0) reds[t >> 6] = s;
  __syncthreads();
  s = reds[0] + reds[1] + reds[2] + reds[3];
  const float inv = 1.f / s;

  pk.x = (unsigned int)f2bf(e[0] * inv) | ((unsigned int)f2bf(e[1] * inv) << 16);
  pk.y = (unsigned int)f2bf(e[2] * inv) | ((unsigned int)f2bf(e[3] * inv) << 16);
  pk.z = (unsigned int)f2bf(e[4] * inv) | ((unsigned int)f2bf(e[5] * inv) << 16);
  pk.w = (unsigned int)f2bf(e[6] * inv) | ((unsigned int)f2bf(e[7] * inv) << 16);
  ((uint4*)p)[t] = pk;
}

// ---------------------------------------------------------------------------
// Flat f32 -> bf16 cast (vectorized, grid-stride).
// ---------------------------------------------------------------------------
__global__ __launch_bounds__(256)
void cast_flat(const float* __restrict__ in, unsigned short* __restrict__ out, int n4)
{
  int idx = blockIdx.x * 256 + threadIdx.x;
  const int stride = gridDim.x * 256;
  for (; idx < n4; idx += stride) {
    float4 v = ((const float4*)in)[idx];
    ushort4 o;
    o.x = f2bf(v.x); o.y = f2bf(v.y); o.z = f2bf(v.z); o.w = f2bf(v.w);
    ((ushort4*)out)[idx] = o;
  }
}

// ---------------------------------------------------------------------------
// Transpose + cast: in f32 [Z][R][C] -> out bf16 [Z][C][R]. Block (32,8).
// ---------------------------------------------------------------------------
__global__ __launch_bounds__(256)
void transpose_cast(const float* __restrict__ in, unsigned short* __restrict__ out,
                    int R, int C)
{
  __shared__ float tile[32][33];
  const int z = blockIdx.z;
  const float* src = in + (long long)z * R * C;
  unsigned short* dst = out + (long long)z * R * C;
  const int tx = threadIdx.x, ty = threadIdx.y;
  const int c0 = blockIdx.x * 32, r0 = blockIdx.y * 32;
#pragma unroll
  for (int k = 0; k < 4; ++k)
    tile[ty + 8 * k][tx] = src[(long long)(r0 + ty + 8 * k) * C + c0 + tx];
  __syncthreads();
#pragma unroll
  for (int k = 0; k < 4; ++k)
    dst[(long long)(c0 + ty + 8 * k) * R + r0 + tx] = f2bf(tile[tx][ty + 8 * k]);
}

// ---------------------------------------------------------------------------
// Launch
// ---------------------------------------------------------------------------
extern "C" void kernel_launch(void* const* d_in, const int* in_sizes, int n_in,
                              void* d_out, int out_size, void* d_ws, size_t ws_size,
                              hipStream_t stream)
{
  const float* X = (const float*)d_in[0];
  const float* Y = (const float*)d_in[1];
  const float* Kw = (const float*)d_in[2];
  const float* Qw = (const float*)d_in[3];
  const float* g1 = (const float*)d_in[4];
  const float* b1 = (const float*)d_in[5];
  const float* g2 = (const float*)d_in[6];
  const float* b2 = (const float*)d_in[7];
  float* out = (float*)d_out;

  // workspace layout (196 MB):
  //  [0,64M)       temp f32 proj output  /  later: alpha bf16 [8,2048,2048]
  //  [64M,96M)     keys bf16 [16384,1024]
  //  [96M,128M)    X bf16 [16384,1024]
  //  [128M,160M)   Y bf16 (proj1 A), later overwritten by queries bf16
  //  [160M,192M)   Yt bf16 [8,1024,2048]
  //  [192M,194M)   Kt bf16 [1024,1024]
  //  [194M,196M)   Qt bf16 [1024,1024]
  char* ws = (char*)d_ws;
  float* tempf = (float*)ws;
  unsigned short* alpha = (unsigned short*)ws;
  unsigned short* keys = (unsigned short*)(ws + (64ll << 20));
  unsigned short* xb   = (unsigned short*)(ws + (96ll << 20));
  unsigned short* ybq  = (unsigned short*)(ws + (128ll << 20));
  unsigned short* yt   = (unsigned short*)(ws + (160ll << 20));
  unsigned short* ktw  = (unsigned short*)(ws + (192ll << 20));
  unsigned short* qtw  = (unsigned short*)(ws + (194ll << 20));

  const int n4 = 16777216 / 4;  // 8*2048*1024 / 4

  // 1. casts
  cast_flat<<<2048, 256, 0, stream>>>(Y, ybq, n4);
  cast_flat<<<2048, 256, 0, stream>>>(X, xb, n4);
  transpose_cast<<<dim3(32, 32, 1), dim3(32, 8), 0, stream>>>(Kw, ktw, 1024, 1024);
  transpose_cast<<<dim3(32, 32, 1), dim3(32, 8), 0, stream>>>(Qw, qtw, 1024, 1024);
  transpose_cast<<<dim3(32, 64, 8), dim3(32, 8), 0, stream>>>(Y, yt, 2048, 1024);

  // 2. keys = LN(Y @ K)   — 256² tiles: grid 4x64 = 256 blocks
  gemm256<0><<<256, 512, 0, stream>>>(
      ybq, ktw, tempf, 1024, 1024, 1024, 1024, 0, 0, 0, 1.f, 4, 64);
  ln_bf16<<<16384, 256, 0, stream>>>(tempf, keys, g1, b1);

  // 3. queries = LN(X @ Q)   (queries overwrite the Ybf16 region)
  gemm256<0><<<256, 512, 0, stream>>>(
      xb, qtw, tempf, 1024, 1024, 1024, 1024, 0, 0, 0, 1.f, 4, 64);
  ln_bf16<<<16384, 256, 0, stream>>>(tempf, ybq, g2, b2);

  // 4. alpha = queries @ keys^T / 1024  (bf16) — grid 8x8x8 = 512 blocks
  gemm256<1><<<512, 512, 0, stream>>>(
      ybq, keys, alpha, 1024, 1024, 1024, 2048,
      2048ll * 1024, 2048ll * 1024, 2048ll * 2048, 1.f / 1024.f, 8, 8);

  // 5. softmax rows
  softmax_bf16<<<16384, 256, 0, stream>>>(alpha);

  // 6. out = alpha @ Y   (B^T = Yt) — grid 4x8x8 = 256 blocks
  gemm256<0><<<256, 512, 0, stream>>>(
      alpha, yt, out, 2048, 2048, 2048, 1024,
      2048ll * 2048, 1024ll * 2048, 2048ll * 1024, 1.f, 4, 8);
}

// Round 6
// 482.436 us; speedup vs baseline: 1.1796x; 1.0243x over previous
//
#include <hip/hip_runtime.h>
#include <hip/hip_bf16.h>
#include <stdint.h>

// ---------------------------------------------------------------------------
// Types / helpers
// ---------------------------------------------------------------------------
typedef __attribute__((ext_vector_type(8))) short bf16x8;
typedef __attribute__((ext_vector_type(4))) float f32x4;

#define GLB_AS __attribute__((address_space(1)))
#define LDS_AS __attribute__((address_space(3)))

__device__ __forceinline__ void g2l16(const void* g, void* l) {
  __builtin_amdgcn_global_load_lds((const GLB_AS void*)g, (LDS_AS void*)l, 16, 0, 0);
}

__device__ __forceinline__ unsigned short f2bf(float f) {
  union { __hip_bfloat16 h; unsigned short u; } cv;
  cv.h = __float2bfloat16(f);
  return cv.u;
}
__device__ __forceinline__ float bf2f(unsigned int u) {
  return __uint_as_float(u << 16);
}

// ---------------------------------------------------------------------------
// 256x256-tile GEMM, 8 waves (2M x 4N), K-step 32, 4-deep LDS pipeline.
//   C[M,N] = A[M,K](bf16 rm) * Bt[N,K]^T(bf16 rm), f32 accum.
// Per K-step: {12 ds_read_b128 + stage A,B(t+3)} | barrier | 32 MFMA
// (setprio-wrapped) | counted vmcnt (never 0 mid-loop) | barrier.
// LDS slot layout: [256 rows][32 cols bf16] (64B rows, 4 x 16B slots).
// Swizzle: phys_slot = (log_slot + (row>>1)) & 3  -> bank-quad =
// 4*(r&1) + ((l4+(r>>1))&3), period 8 in r -> 2 lanes/quad (free, m136).
// Staging: linear LDS dest (tid*16); global source pre-inverse-swizzled
// with the same involution (q_log = (phys - (row>>1)) & 3).
// ---------------------------------------------------------------------------
template <int OUT_BF16>
__global__ __launch_bounds__(512, 2)
void gemm256(const unsigned short* __restrict__ A,
             const unsigned short* __restrict__ Bt,
             void* __restrict__ C,
             int K, int lda, int ldb, int ldc,
             long long sA, long long sB, long long sC,
             float scale, int gx, int gy)
{
  __shared__ __attribute__((aligned(16))) char lds[131072];  // 4 slots x (A 16K + B 16K)

  // XCD-chunked bijective swizzle (grid always a multiple of 8 here).
  const int nwg = gridDim.x;
  const int bid = blockIdx.x;
  const int wgid = (bid & 7) * (nwg >> 3) + (bid >> 3);
  const int bx = wgid % gx;
  const int rest = wgid / gx;
  const int by = rest % gy;
  const int bz = rest / gy;

  const int tid = threadIdx.x;
  const int lane = tid & 63, wid = tid >> 6;
  const int wr = wid >> 2, wc = wid & 3;           // wave tile: 128 rows x 64 cols
  const int l15 = lane & 15, l4 = lane >> 4;

  const unsigned short* Ab = A + (long long)bz * sA + (long long)by * 256 * lda;
  const unsigned short* Bb = Bt + (long long)bz * sB + (long long)bx * 256 * ldb;

  // staging: 2 chunks/thread per 16KB half (1024 chunks of 16B).
  // chunk c: row = c>>2, phys slot p = c&3, logical k-group q = (p-(row>>1))&3.
  const int c0 = tid, c1 = 512 + tid;
  const int r0 = c0 >> 2, q0 = ((c0 & 3) - (r0 >> 1)) & 3;
  const int r1 = c1 >> 2, q1 = ((c1 & 3) - (r1 >> 1)) & 3;
  const unsigned short* gA0 = Ab + (long long)r0 * lda + q0 * 8;
  const unsigned short* gA1 = Ab + (long long)r1 * lda + q1 * 8;
  const unsigned short* gB0 = Bb + (long long)r0 * ldb + q0 * 8;
  const unsigned short* gB1 = Bb + (long long)r1 * ldb + q1 * 8;
  const int dc0 = c0 * 16, dc1 = c1 * 16;

#define STAGE_A(slot_, kt_)                                        \
  do {                                                             \
    char* base_ = lds + (slot_) * 32768;                           \
    g2l16(gA0 + (kt_) * 32, base_ + dc0);                          \
    g2l16(gA1 + (kt_) * 32, base_ + dc1);                          \
  } while (0)
#define STAGE_B(slot_, kt_)                                        \
  do {                                                             \
    char* base_ = lds + (slot_) * 32768 + 16384;                   \
    g2l16(gB0 + (kt_) * 32, base_ + dc0);                          \
    g2l16(gB1 + (kt_) * 32, base_ + dc1);                          \
  } while (0)

  f32x4 acc[8][4];
#pragma unroll
  for (int m = 0; m < 8; ++m)
#pragma unroll
    for (int n = 0; n < 4; ++n) acc[m][n] = f32x4{0.f, 0.f, 0.f, 0.f};

  const int nst = K / 32;

  // prologue: stage steps 0,1,2
  STAGE_A(0, 0); STAGE_B(0, 0);
  STAGE_A(1, 1); STAGE_B(1, 1);
  STAGE_A(2, 2); STAGE_B(2, 2);
  asm volatile("s_waitcnt vmcnt(8)" ::: "memory");   // step-0 A,B landed
  __builtin_amdgcn_sched_barrier(0);
  __builtin_amdgcn_s_barrier();
  __builtin_amdgcn_sched_barrier(0);

  bf16x8 a[8], b[4];
  for (int t = 0; t < nst; ++t) {
    const int s = t & 3;
    const char* sbA = lds + s * 32768;
    const char* sbB = sbA + 16384;

    // ---- reads (12 x ds_read_b128, 2-way bank quads) + prefetch t+3
#pragma unroll
    for (int m = 0; m < 8; ++m) {
      int r = wr * 128 + m * 16 + l15;
      a[m] = *(const bf16x8*)(sbA + r * 64 + (((l4 + (r >> 1)) & 3) << 4));
    }
#pragma unroll
    for (int n = 0; n < 4; ++n) {
      int r = wc * 64 + n * 16 + l15;
      b[n] = *(const bf16x8*)(sbB + r * 64 + (((l4 + (r >> 1)) & 3) << 4));
    }
    if (t + 3 < nst) { STAGE_A((t + 3) & 3, t + 3); STAGE_B((t + 3) & 3, t + 3); }
    __builtin_amdgcn_sched_barrier(0);
    __builtin_amdgcn_s_barrier();
    __builtin_amdgcn_sched_barrier(0);

    // ---- 32 MFMA cluster
    __builtin_amdgcn_s_setprio(1);
#pragma unroll
    for (int m = 0; m < 8; ++m)
#pragma unroll
      for (int n = 0; n < 4; ++n)
        acc[m][n] = __builtin_amdgcn_mfma_f32_16x16x32_bf16(a[m], b[n], acc[m][n], 0, 0, 0);
    __builtin_amdgcn_s_setprio(0);

    // counted wait: confirm next step's slot before the step-end barrier.
    // outstanding = 4 per staged-ahead step; drain oldest 4 only.
    if (t + 1 < nst) {
      int f = nst - 1 - t; if (f > 3) f = 3;
      if (f == 3)      asm volatile("s_waitcnt vmcnt(8)" ::: "memory");
      else if (f == 2) asm volatile("s_waitcnt vmcnt(4)" ::: "memory");
      else             asm volatile("s_waitcnt vmcnt(0)" ::: "memory");
    }
    __builtin_amdgcn_sched_barrier(0);
    __builtin_amdgcn_s_barrier();
    __builtin_amdgcn_sched_barrier(0);
  }
#undef STAGE_A
#undef STAGE_B

  // epilogue: C/D layout col = n0+n*16+l15, row = m0+m*16+l4*4+i  [m89]
  const long long m0 = (long long)by * 256 + wr * 128;
  const long long n0 = (long long)bx * 256 + wc * 64;
  if (OUT_BF16) {
    unsigned short* Cc = (unsigned short*)C + (long long)bz * sC;
#pragma unroll
    for (int m = 0; m < 8; ++m)
#pragma unroll
      for (int n = 0; n < 4; ++n)
#pragma unroll
        for (int i = 0; i < 4; ++i) {
          long long r = m0 + m * 16 + l4 * 4 + i;
          long long col = n0 + n * 16 + l15;
          Cc[r * ldc + col] = f2bf(acc[m][n][i] * scale);
        }
  } else {
    float* Cf = (float*)C + (long long)bz * sC;
#pragma unroll
    for (int m = 0; m < 8; ++m)
#pragma unroll
      for (int n = 0; n < 4; ++n)
#pragma unroll
        for (int i = 0; i < 4; ++i) {
          long long r = m0 + m * 16 + l4 * 4 + i;
          long long col = n0 + n * 16 + l15;
          Cf[r * ldc + col] = acc[m][n][i];
        }
  }
}

// ---------------------------------------------------------------------------
// LayerNorm over rows of 1024 bf16 -> bf16 (g,b applied). 1 block / row.
// ---------------------------------------------------------------------------
__global__ __launch_bounds__(256)
void ln_bf16(const unsigned short* __restrict__ in, unsigned short* __restrict__ out,
             const float* __restrict__ g, const float* __restrict__ b)
{
  const long long row = blockIdx.x;
  const int t = threadIdx.x;
  const uint2 pk = ((const uint2*)(in + row * 1024))[t];
  float v[4];
  v[0] = bf2f(pk.x & 0xffffu); v[1] = bf2f(pk.x >> 16);
  v[2] = bf2f(pk.y & 0xffffu); v[3] = bf2f(pk.y >> 16);
  float s = v[0] + v[1] + v[2] + v[3];
  float ss = v[0] * v[0] + v[1] * v[1] + v[2] * v[2] + v[3] * v[3];
#pragma unroll
  for (int o = 32; o >= 1; o >>= 1) {
    s += __shfl_xor(s, o);
    ss += __shfl_xor(ss, o);
  }
  __shared__ float red[8];
  if ((t & 63) == 0) { red[t >> 6] = s; red[4 + (t >> 6)] = ss; }
  __syncthreads();
  s = red[0] + red[1] + red[2] + red[3];
  ss = red[4] + red[5] + red[6] + red[7];
  const float mean = s * (1.f / 1024.f);
  const float var = ss * (1.f / 1024.f) - mean * mean;
  const float rs = rsqrtf(var + 1e-5f);
  const float4 gv = ((const float4*)g)[t];
  const float4 bv = ((const float4*)b)[t];
  ushort4 o4;
  o4.x = f2bf((v[0] - mean) * rs * gv.x + bv.x);
  o4.y = f2bf((v[1] - mean) * rs * gv.y + bv.y);
  o4.z = f2bf((v[2] - mean) * rs * gv.z + bv.z);
  o4.w = f2bf((v[3] - mean) * rs * gv.w + bv.w);
  ((ushort4*)(out + row * 1024))[t] = o4;
}

// ---------------------------------------------------------------------------
// Row softmax over 2048 bf16, in place. 1 block / row, 8 elems / thread.
// ---------------------------------------------------------------------------
__global__ __launch_bounds__(256)
void softmax_bf16(unsigned short* __restrict__ a)
{
  const long long row = blockIdx.x;
  unsigned short* p = a + row * 2048;
  const int t = threadIdx.x;
  uint4 pk = ((const uint4*)p)[t];
  float v[8];
  v[0] = bf2f(pk.x & 0xffffu); v[1] = bf2f(pk.x >> 16);
  v[2] = bf2f(pk.y & 0xffffu); v[3] = bf2f(pk.y >> 16);
  v[4] = bf2f(pk.z & 0xffffu); v[5] = bf2f(pk.z >> 16);
  v[6] = bf2f(pk.w & 0xffffu); v[7] = bf2f(pk.w >> 16);

  float m = v[0];
#pragma unroll
  for (int i = 1; i < 8; ++i) m = fmaxf(m, v[i]);
#pragma unroll
  for (int o = 32; o >= 1; o >>= 1) m = fmaxf(m, __shfl_xor(m, o));
  __shared__ float redm[4];
  if ((t & 63) == 0) redm[t >> 6] = m;
  __syncthreads();
  m = fmaxf(fmaxf(redm[0], redm[1]), fmaxf(redm[2], redm[3]));

  float e[8];
  float s = 0.f;
#pragma unroll
  for (int i = 0; i < 8; ++i) { e[i] = __expf(v[i] - m); s += e[i]; }
#pragma unroll
  for (int o = 32; o >= 1; o >>= 1) s += __shfl_xor(s, o);
  __shared__ float reds[4];
  if ((t & 63) == 0) reds[t >> 6] = s;
  __syncthreads();
  s = reds[0] + reds[1] + reds[2] + reds[3];
  const float inv = 1.f / s;

  pk.x = (unsigned int)f2bf(e[0] * inv) | ((unsigned int)f2bf(e[1] * inv) << 16);
  pk.y = (unsigned int)f2bf(e[2] * inv) | ((unsigned int)f2bf(e[3] * inv) << 16);
  pk.z = (unsigned int)f2bf(e[4] * inv) | ((unsigned int)f2bf(e[5] * inv) << 16);
  pk.w = (unsigned int)f2bf(e[6] * inv) | ((unsigned int)f2bf(e[7] * inv) << 16);
  ((uint4*)p)[t] = pk;
}

// ---------------------------------------------------------------------------
// Flat f32 -> bf16 cast (vectorized, grid-stride).
// ---------------------------------------------------------------------------
__global__ __launch_bounds__(256)
void cast_flat(const float* __restrict__ in, unsigned short* __restrict__ out, int n4)
{
  int idx = blockIdx.x * 256 + threadIdx.x;
  const int stride = gridDim.x * 256;
  for (; idx < n4; idx += stride) {
    float4 v = ((const float4*)in)[idx];
    ushort4 o;
    o.x = f2bf(v.x); o.y = f2bf(v.y); o.z = f2bf(v.z); o.w = f2bf(v.w);
    ((ushort4*)out)[idx] = o;
  }
}

// ---------------------------------------------------------------------------
// Transpose + cast: in f32 [Z][R][C] -> out bf16 [Z][C][R]. Block (32,8).
// ---------------------------------------------------------------------------
__global__ __launch_bounds__(256)
void transpose_cast(const float* __restrict__ in, unsigned short* __restrict__ out,
                    int R, int C)
{
  __shared__ float tile[32][33];
  const int z = blockIdx.z;
  const float* src = in + (long long)z * R * C;
  unsigned short* dst = out + (long long)z * R * C;
  const int tx = threadIdx.x, ty = threadIdx.y;
  const int c0 = blockIdx.x * 32, r0 = blockIdx.y * 32;
#pragma unroll
  for (int k = 0; k < 4; ++k)
    tile[ty + 8 * k][tx] = src[(long long)(r0 + ty + 8 * k) * C + c0 + tx];
  __syncthreads();
#pragma unroll
  for (int k = 0; k < 4; ++k)
    dst[(long long)(c0 + ty + 8 * k) * R + r0 + tx] = f2bf(tile[tx][ty + 8 * k]);
}

// ---------------------------------------------------------------------------
// Launch
// ---------------------------------------------------------------------------
extern "C" void kernel_launch(void* const* d_in, const int* in_sizes, int n_in,
                              void* d_out, int out_size, void* d_ws, size_t ws_size,
                              hipStream_t stream)
{
  const float* X = (const float*)d_in[0];
  const float* Y = (const float*)d_in[1];
  const float* Kw = (const float*)d_in[2];
  const float* Qw = (const float*)d_in[3];
  const float* g1 = (const float*)d_in[4];
  const float* b1 = (const float*)d_in[5];
  const float* g2 = (const float*)d_in[6];
  const float* b2 = (const float*)d_in[7];
  float* out = (float*)d_out;

  // workspace layout (196 MB):
  //  [0,64M)       temp bf16 proj output [16384,1024] (32M used) /
  //                later: alpha bf16 [8,2048,2048] (64M)
  //  [64M,96M)     keys bf16 [16384,1024]
  //  [96M,128M)    X bf16 [16384,1024]
  //  [128M,160M)   Y bf16 (proj1 A), later overwritten by queries bf16
  //  [160M,192M)   Yt bf16 [8,1024,2048]
  //  [192M,194M)   Kt bf16 [1024,1024]
  //  [194M,196M)   Qt bf16 [1024,1024]
  char* ws = (char*)d_ws;
  unsigned short* tempb = (unsigned short*)ws;
  unsigned short* alpha = (unsigned short*)ws;
  unsigned short* keys = (unsigned short*)(ws + (64ll << 20));
  unsigned short* xb   = (unsigned short*)(ws + (96ll << 20));
  unsigned short* ybq  = (unsigned short*)(ws + (128ll << 20));
  unsigned short* yt   = (unsigned short*)(ws + (160ll << 20));
  unsigned short* ktw  = (unsigned short*)(ws + (192ll << 20));
  unsigned short* qtw  = (unsigned short*)(ws + (194ll << 20));

  const int n4 = 16777216 / 4;  // 8*2048*1024 / 4

  // 1. casts
  cast_flat<<<2048, 256, 0, stream>>>(Y, ybq, n4);
  cast_flat<<<2048, 256, 0, stream>>>(X, xb, n4);
  transpose_cast<<<dim3(32, 32, 1), dim3(32, 8), 0, stream>>>(Kw, ktw, 1024, 1024);
  transpose_cast<<<dim3(32, 32, 1), dim3(32, 8), 0, stream>>>(Qw, qtw, 1024, 1024);
  transpose_cast<<<dim3(32, 64, 8), dim3(32, 8), 0, stream>>>(Y, yt, 2048, 1024);

  // 2. keys = LN(Y @ K)   — 256² tiles: grid 4x64 = 256 blocks (bf16 temp)
  gemm256<1><<<256, 512, 0, stream>>>(
      ybq, ktw, tempb, 1024, 1024, 1024, 1024, 0, 0, 0, 1.f, 4, 64);
  ln_bf16<<<16384, 256, 0, stream>>>(tempb, keys, g1, b1);

  // 3. queries = LN(X @ Q)   (queries overwrite the Ybf16 region)
  gemm256<1><<<256, 512, 0, stream>>>(
      xb, qtw, tempb, 1024, 1024, 1024, 1024, 0, 0, 0, 1.f, 4, 64);
  ln_bf16<<<16384, 256, 0, stream>>>(tempb, ybq, g2, b2);

  // 4. alpha = queries @ keys^T / 1024  (bf16) — grid 8x8x8 = 512 blocks
  gemm256<1><<<512, 512, 0, stream>>>(
      ybq, keys, alpha, 1024, 1024, 1024, 2048,
      2048ll * 1024, 2048ll * 1024, 2048ll * 2048, 1.f / 1024.f, 8, 8);

  // 5. softmax rows
  softmax_bf16<<<16384, 256, 0, stream>>>(alpha);

  // 6. out = alpha @ Y   (B^T = Yt) — grid 4x8x8 = 256 blocks
  gemm256<0><<<256, 512, 0, stream>>>(
      alpha, yt, out, 2048, 2048, 2048, 1024,
      2048ll * 2048, 1024ll * 2048, 2048ll * 1024, 1.f, 4, 8);
}